// Round 4
// baseline (551.119 us; speedup 1.0000x reference)
//
#include <hip/hip_runtime.h>

typedef unsigned short u16;
typedef unsigned int u32;
typedef __attribute__((ext_vector_type(8))) short short8v;
typedef __attribute__((ext_vector_type(4))) float float4v;
typedef __attribute__((ext_vector_type(4))) int   int4v;

#define N_NODES 8192
#define D_IN    512
#define D_OUT   128
#define SLOPEF  0.2f
#define LOG2E   1.4426950408889634f
#define NSEG    4
#define SEGCOLS 2048   // N_NODES / NSEG
#define NCHUNK  8      // SEGCOLS / 256

static __device__ __forceinline__ u16 f2bf(float f) {
    union { float f; unsigned int i; } v; v.f = f;
    unsigned int r = v.i + 0x7fff + ((v.i >> 16) & 1);
    return (u16)(r >> 16);
}
static __device__ __forceinline__ void lds_barrier() {
    asm volatile("s_waitcnt lgkmcnt(0)" ::: "memory");
    __builtin_amdgcn_s_barrier();
    asm volatile("" ::: "memory");
}

// ---------------- Kernel B: bitpack adj (256 MB -> 8 MB), pure streaming ----------------
__global__ __launch_bounds__(256) void kb_pack(
        const int* __restrict__ adj, unsigned long long* __restrict__ mask64)
{
    const int lane = threadIdx.x & 63;
    const int gw = (blockIdx.x * 256 + threadIdx.x) >> 6;   // global wave id, 0..4095
    const int NW = (1024 * 256) / 64;                        // 4096 waves
    const int NITER = (N_NODES * (N_NODES / 64)) / NW;       // 256
    #pragma unroll 4
    for (int it = 0; it < NITER; ++it) {
        const size_t w64 = (size_t)gw + (size_t)NW * it;
        const int v = adj[w64 * 64 + lane];
        const unsigned long long b = __ballot(v > 0);
        if (lane == 0) mask64[w64] = b;
    }
}

// ---------------- Kernel 1: Wh = h@W (fp32 in), WhT bf16 [128][8192], f1, f2 (x log2e) ----------------
__global__ __launch_bounds__(256, 2) void k1_proj(
        const float* __restrict__ h, const float* __restrict__ W,
        const float* __restrict__ a, u16* __restrict__ WhT,
        float* __restrict__ f1, float* __restrict__ f2)
{
    __shared__ float hs[16 * D_IN];     // 32 KB
    __shared__ float buf[16 * 128];     // 8 KB
    __shared__ float part[16][17];
    const int tid = threadIdx.x;
    const int rowbase = blockIdx.x * 16;

    const float4v* hsrc = (const float4v*)(h + (size_t)rowbase * D_IN);
    #pragma unroll
    for (int i = 0; i < 8; i++) {
        *(float4v*)&hs[(tid + 256 * i) * 4] = hsrc[tid + 256 * i];
    }
    __syncthreads();

    const int c  = tid & 127;   // output feature
    const int rh = tid >> 7;    // row half (8 rows each)
    float acc[8];
    #pragma unroll
    for (int rr = 0; rr < 8; rr++) acc[rr] = 0.f;

    for (int k = 0; k < D_IN; k += 4) {
        float wv[4];
        #pragma unroll
        for (int kk = 0; kk < 4; kk++) wv[kk] = W[(k + kk) * D_OUT + c];
        #pragma unroll
        for (int rr = 0; rr < 8; rr++) {
            float4v hv = *(const float4v*)&hs[(rh * 8 + rr) * D_IN + k];
            acc[rr] += hv[0] * wv[0];
            acc[rr] += hv[1] * wv[1];
            acc[rr] += hv[2] * wv[2];
            acc[rr] += hv[3] * wv[3];
        }
    }

    {
        short8v pack;
        #pragma unroll
        for (int rr = 0; rr < 8; rr++) pack[rr] = (short)f2bf(acc[rr]);
        *(short8v*)(WhT + (size_t)c * N_NODES + rowbase + rh * 8) = pack;
    }

    const float a1 = a[c];
    const float a2 = a[D_OUT + c];

    #pragma unroll
    for (int rr = 0; rr < 8; rr++) buf[(rh * 8 + rr) * 128 + c] = acc[rr] * a1;
    __syncthreads();
    {
        const int row = tid >> 4, seg = tid & 15;
        float p = 0.f;
        #pragma unroll
        for (int e = 0; e < 8; e++) p += buf[row * 128 + seg * 8 + e];
        part[row][seg] = p;
    }
    __syncthreads();
    if (tid < 16) {
        float s = 0.f;
        #pragma unroll
        for (int j = 0; j < 16; j++) s += part[tid][j];
        f1[rowbase + tid] = s * LOG2E;       // pre-scaled for exp2
    }
    __syncthreads();
    #pragma unroll
    for (int rr = 0; rr < 8; rr++) buf[(rh * 8 + rr) * 128 + c] = acc[rr] * a2;
    __syncthreads();
    {
        const int row = tid >> 4, seg = tid & 15;
        float p = 0.f;
        #pragma unroll
        for (int e = 0; e < 8; e++) p += buf[row * 128 + seg * 8 + e];
        part[row][seg] = p;
    }
    __syncthreads();
    if (tid < 16) {
        float s = 0.f;
        #pragma unroll
        for (int j = 0; j < 16; j++) s += part[tid][j];
        f2[rowbase + tid] = s * LOG2E;       // pre-scaled for exp2
    }
}

// ---------------- Kernel 2: fused mask+exp2 + partial PV via MFMA (bitmask input) ----------------
// Block = 32 rows x 2048-col segment. Thread (r,g) owns 32 consecutive cols per 256-chunk.
__global__ __launch_bounds__(256, 4) void k2_attn(
        const u32* __restrict__ mask, const u16* __restrict__ WhT,
        const float* __restrict__ f1g, const float* __restrict__ f2g,
        float* __restrict__ numw, float* __restrict__ denw)
{
    __shared__ short Pt[32 * 264];       // 16.9 KB, row stride 264 shorts
    __shared__ float f2s[2304];          // 2048 + 4-float pad per 32 -> bank-spread
    __shared__ float f1s[32];
    __shared__ float rs[32][9];
    __shared__ float ssum[32];

    const int tid = threadIdx.x;
    const int rb  = blockIdx.x >> 2;
    const int seg = blockIdx.x & 3;
    const int rowbase = rb * 32;
    const int colbase = seg * SEGCOLS;
    const int r = tid >> 3, g = tid & 7;
    const int lane = tid & 63, w = tid >> 6;
    const int quad = lane >> 4, m16 = lane & 15;

    if (tid < 32) f1s[tid] = f1g[rowbase + tid];
    #pragma unroll
    for (int i = 0; i < 2; i++) {
        const int idx = (tid + 256 * i) * 4;
        *(float4v*)&f2s[idx + ((idx >> 5) << 2)] = *(const float4v*)&f2g[colbase + idx];
    }

    const u32* mrow = mask + (size_t)(rowbase + r) * (N_NODES / 32) + seg * (SEGCOLS / 32);
    u32 mcur = mrow[g];    // chunk 0 word: cols g*32..g*32+31

    float4v acc[2][2];
    #pragma unroll
    for (int mt = 0; mt < 2; mt++)
        #pragma unroll
        for (int nt = 0; nt < 2; nt++) {
            acc[mt][nt][0] = 0.f; acc[mt][nt][1] = 0.f;
            acc[mt][nt][2] = 0.f; acc[mt][nt][3] = 0.f;
        }
    float ls0 = 0.f, ls1 = 0.f, ls2 = 0.f, ls3 = 0.f;

    __syncthreads();   // f1s/f2s ready

    for (int jc = 0; jc < NCHUNK; jc++) {
        u32 mnext = 0;
        if (jc + 1 < NCHUNK) mnext = mrow[(jc + 1) * 8 + g];

        // ---- weight phase: 32 consecutive cols per thread ----
        const float f1v = f1s[r];
        const float* f2p = &f2s[jc * 288 + g * 36];
        u32 packed[16];
        #pragma unroll
        for (int i = 0; i < 8; i++) {
            const float4v fv = *(const float4v*)&f2p[i * 4];
            u32 wb[4];
            #pragma unroll
            for (int e = 0; e < 4; e++) {
                const int idx = i * 4 + e;
                const int sel = ((int)(mcur << (31 - idx))) >> 31;   // 0 or -1
                float x = f1v + fv[e];
                x = fmaxf(x, SLOPEF * x);                            // leaky_relu (log2 domain)
                const float ex = __builtin_amdgcn_exp2f(x);
                const u32 wt = __float_as_uint(ex) & ((u32)sel & 0xffff0000u); // masked + bf16-trunc
                wb[e] = wt;
                if (e == 0) ls0 += __uint_as_float(wt);
                else if (e == 1) ls1 += __uint_as_float(wt);
                else if (e == 2) ls2 += __uint_as_float(wt);
                else ls3 += __uint_as_float(wt);
            }
            packed[i * 2]     = __builtin_amdgcn_perm(wb[1], wb[0], 0x07060302);
            packed[i * 2 + 1] = __builtin_amdgcn_perm(wb[3], wb[2], 0x07060302);
        }
        {
            int* pdst = (int*)&Pt[r * 264 + g * 32];
            #pragma unroll
            for (int q = 0; q < 4; q++) {
                int4v st;
                st[0] = (int)packed[q * 4 + 0]; st[1] = (int)packed[q * 4 + 1];
                st[2] = (int)packed[q * 4 + 2]; st[3] = (int)packed[q * 4 + 3];
                *(int4v*)&pdst[q * 4] = st;
            }
        }
        mcur = mnext;
        lds_barrier();

        // ---- MFMA phase: acc += P[32 x 256] @ Wh[256 x 128] (this wave's 32 feature cols) ----
        {
            const u16* b0p = WhT + (size_t)(w * 32 + m16) * N_NODES + colbase + jc * 256 + quad * 8;
            const u16* b1p = b0p + 16 * N_NODES;
            const short* a0p = &Pt[m16 * 264 + quad * 8];
            const short* a1p = a0p + 16 * 264;
            #pragma unroll
            for (int ks = 0; ks < 8; ks++) {
                const int ko = ks * 32;
                const short8v af0 = *(const short8v*)(a0p + ko);
                const short8v af1 = *(const short8v*)(a1p + ko);
                const short8v bv0 = *(const short8v*)(b0p + ko);
                const short8v bv1 = *(const short8v*)(b1p + ko);
                acc[0][0] = __builtin_amdgcn_mfma_f32_16x16x32_bf16(af0, bv0, acc[0][0], 0, 0, 0);
                acc[0][1] = __builtin_amdgcn_mfma_f32_16x16x32_bf16(af0, bv1, acc[0][1], 0, 0, 0);
                acc[1][0] = __builtin_amdgcn_mfma_f32_16x16x32_bf16(af1, bv0, acc[1][0], 0, 0, 0);
                acc[1][1] = __builtin_amdgcn_mfma_f32_16x16x32_bf16(af1, bv1, acc[1][1], 0, 0, 0);
            }
        }
        lds_barrier();
    }

    // per-row partial denominator
    rs[r][g] = (ls0 + ls1) + (ls2 + ls3);
    __syncthreads();
    if (tid < 32) {
        float s = 0.f;
        #pragma unroll
        for (int j = 0; j < 8; j++) s += rs[tid][j];
        ssum[tid] = s;
        denw[(size_t)(rowbase + tid) * NSEG + seg] = s;
    }
    __syncthreads();

    // epilogue: write partial numerator. C/D layout col=lane&15, row=quad*4+reg
    #pragma unroll
    for (int mt = 0; mt < 2; mt++) {
        #pragma unroll
        for (int nt = 0; nt < 2; nt++) {
            const int cl = w * 32 + nt * 16 + m16;
            #pragma unroll
            for (int reg = 0; reg < 4; reg++) {
                const int rl = mt * 16 + quad * 4 + reg;
                numw[((size_t)(rowbase + rl) * NSEG + seg) * D_OUT + cl] = acc[mt][nt][reg];
            }
        }
    }
}

// ---------------- Kernel 3: reduce partials, divide, write output ----------------
__global__ __launch_bounds__(256) void k3_reduce(
        const float* __restrict__ numw, const float* __restrict__ denw,
        float* __restrict__ out)
{
    const int tid = threadIdx.x;
    const int row = blockIdx.x * 2 + (tid >> 7);
    const int c   = tid & 127;
    float s = 0.f, d = 0.f;
    #pragma unroll
    for (int sg = 0; sg < NSEG; sg++) {
        s += numw[((size_t)row * NSEG + sg) * D_OUT + c];
        d += denw[(size_t)row * NSEG + sg];
    }
    out[(size_t)row * D_OUT + c] = s / d;
}

extern "C" void kernel_launch(void* const* d_in, const int* in_sizes, int n_in,
                              void* d_out, int out_size, void* d_ws, size_t ws_size,
                              hipStream_t stream) {
    const float* h   = (const float*)d_in[0];
    const int*   adj = (const int*)d_in[1];
    const float* W   = (const float*)d_in[2];
    const float* a   = (const float*)d_in[3];

    char* ws = (char*)d_ws;
    unsigned long long* mask64 = (unsigned long long*)ws;      // 8 MB
    u16*   WhT = (u16*)(ws + (size_t)8 * 1024 * 1024);         // 2 MB
    float* f1  = (float*)(ws + (size_t)10 * 1024 * 1024);      // 32 KB
    float* f2  = f1 + N_NODES;                                 // 32 KB
    float* numw = (float*)(ws + (size_t)12 * 1024 * 1024);     // 16 MB
    float* denw = (float*)(ws + (size_t)28 * 1024 * 1024);     // 128 KB

    kb_pack<<<1024, 256, 0, stream>>>(adj, mask64);
    k1_proj<<<N_NODES / 16, 256, 0, stream>>>(h, W, a, WhT, f1, f2);
    k2_attn<<<(N_NODES / 32) * NSEG, 256, 0, stream>>>((const u32*)mask64, WhT, f1, f2, numw, denw);
    k3_reduce<<<N_NODES / 2, 256, 0, stream>>>(numw, denw, (float*)d_out);
}

// Round 5
// 474.737 us; speedup vs baseline: 1.1609x; 1.1609x over previous
//
#include <hip/hip_runtime.h>

typedef unsigned short u16;
typedef unsigned int u32;
typedef __attribute__((ext_vector_type(8))) short short8v;
typedef __attribute__((ext_vector_type(4))) float float4v;
typedef __attribute__((ext_vector_type(4))) int   int4v;

#define N_NODES 8192
#define D_IN    512
#define D_OUT   128
#define SLOPEF  0.2f
#define LOG2E   1.4426950408889634f
#define NSEG    4
#define SEGCOLS 2048   // N_NODES / NSEG
#define NCHUNK  8      // SEGCOLS / 256

static __device__ __forceinline__ u16 f2bf(float f) {
    union { float f; unsigned int i; } v; v.f = f;
    unsigned int r = v.i + 0x7fff + ((v.i >> 16) & 1);
    return (u16)(r >> 16);
}
static __device__ __forceinline__ void lds_barrier() {
    asm volatile("s_waitcnt lgkmcnt(0)" ::: "memory");
    __builtin_amdgcn_s_barrier();
    asm volatile("" ::: "memory");
}

// ---------------- Kernel B: bitpack adj (256 MB -> 8 MB), deep-pipelined streaming ----------------
// 4096 blocks = 16384 waves; each wave packs 64 contiguous 64-elem words (16 KB read).
// 8 independent loads in flight per wave (one base reg + immediate offsets).
__global__ __launch_bounds__(256) void kb_pack(
        const int* __restrict__ adj, unsigned long long* __restrict__ mask64)
{
    const int lane = threadIdx.x & 63;
    const int gw = (blockIdx.x * 256 + threadIdx.x) >> 6;   // 0..16383
    #pragma unroll
    for (int it = 0; it < 8; ++it) {
        const int* base = adj + ((size_t)gw * 64 + it * 8) * 64 + lane;
        int v[8];
        #pragma unroll
        for (int g = 0; g < 8; g++) v[g] = base[g * 64];    // 8 loads, imm offsets 0..1792B
        unsigned long long b[8];
        #pragma unroll
        for (int g = 0; g < 8; g++) b[g] = __ballot(v[g] > 0);
        unsigned long long myb = b[0];
        #pragma unroll
        for (int g = 1; g < 8; g++) myb = (lane == g) ? b[g] : myb;
        if (lane < 8) mask64[(size_t)gw * 64 + it * 8 + lane] = myb;
    }
}

// ---------------- Kernel 1: Wh = h@W (fp32 in), WhT bf16 [128][8192], f1, f2 (x log2e) ----------------
__global__ __launch_bounds__(256, 2) void k1_proj(
        const float* __restrict__ h, const float* __restrict__ W,
        const float* __restrict__ a, u16* __restrict__ WhT,
        float* __restrict__ f1, float* __restrict__ f2)
{
    __shared__ float hs[16 * D_IN];     // 32 KB
    __shared__ float buf[16 * 128];     // 8 KB
    __shared__ float part[16][17];
    const int tid = threadIdx.x;
    const int rowbase = blockIdx.x * 16;

    const float4v* hsrc = (const float4v*)(h + (size_t)rowbase * D_IN);
    #pragma unroll
    for (int i = 0; i < 8; i++) {
        *(float4v*)&hs[(tid + 256 * i) * 4] = hsrc[tid + 256 * i];
    }
    __syncthreads();

    const int c  = tid & 127;   // output feature
    const int rh = tid >> 7;    // row half (8 rows each)
    float acc[8];
    #pragma unroll
    for (int rr = 0; rr < 8; rr++) acc[rr] = 0.f;

    for (int k = 0; k < D_IN; k += 4) {
        float wv[4];
        #pragma unroll
        for (int kk = 0; kk < 4; kk++) wv[kk] = W[(k + kk) * D_OUT + c];
        #pragma unroll
        for (int rr = 0; rr < 8; rr++) {
            float4v hv = *(const float4v*)&hs[(rh * 8 + rr) * D_IN + k];
            acc[rr] += hv[0] * wv[0];
            acc[rr] += hv[1] * wv[1];
            acc[rr] += hv[2] * wv[2];
            acc[rr] += hv[3] * wv[3];
        }
    }

    {
        short8v pack;
        #pragma unroll
        for (int rr = 0; rr < 8; rr++) pack[rr] = (short)f2bf(acc[rr]);
        *(short8v*)(WhT + (size_t)c * N_NODES + rowbase + rh * 8) = pack;
    }

    const float a1 = a[c];
    const float a2 = a[D_OUT + c];

    #pragma unroll
    for (int rr = 0; rr < 8; rr++) buf[(rh * 8 + rr) * 128 + c] = acc[rr] * a1;
    __syncthreads();
    {
        const int row = tid >> 4, seg = tid & 15;
        float p = 0.f;
        #pragma unroll
        for (int e = 0; e < 8; e++) p += buf[row * 128 + seg * 8 + e];
        part[row][seg] = p;
    }
    __syncthreads();
    if (tid < 16) {
        float s = 0.f;
        #pragma unroll
        for (int j = 0; j < 16; j++) s += part[tid][j];
        f1[rowbase + tid] = s * LOG2E;       // pre-scaled for exp2
    }
    __syncthreads();
    #pragma unroll
    for (int rr = 0; rr < 8; rr++) buf[(rh * 8 + rr) * 128 + c] = acc[rr] * a2;
    __syncthreads();
    {
        const int row = tid >> 4, seg = tid & 15;
        float p = 0.f;
        #pragma unroll
        for (int e = 0; e < 8; e++) p += buf[row * 128 + seg * 8 + e];
        part[row][seg] = p;
    }
    __syncthreads();
    if (tid < 16) {
        float s = 0.f;
        #pragma unroll
        for (int j = 0; j < 16; j++) s += part[tid][j];
        f2[rowbase + tid] = s * LOG2E;       // pre-scaled for exp2
    }
}

// ---------------- Kernel 2: fused mask+exp2 + partial PV via MFMA (bitmask input) ----------------
// Block = 32 rows x 2048-col segment. Thread (r,g) owns 32 consecutive cols per 256-chunk.
__global__ __launch_bounds__(256, 4) void k2_attn(
        const u32* __restrict__ mask, const u16* __restrict__ WhT,
        const float* __restrict__ f1g, const float* __restrict__ f2g,
        float* __restrict__ numw, float* __restrict__ denw)
{
    __shared__ short Pt[32 * 264];       // 16.9 KB, row stride 264 shorts
    __shared__ float f2s[2304];          // 2048 + 4-float pad per 32 -> bank-spread
    __shared__ float f1s[32];
    __shared__ float rs[32][9];
    __shared__ float ssum[32];

    const int tid = threadIdx.x;
    const int rb  = blockIdx.x >> 2;
    const int seg = blockIdx.x & 3;
    const int rowbase = rb * 32;
    const int colbase = seg * SEGCOLS;
    const int r = tid >> 3, g = tid & 7;
    const int lane = tid & 63, w = tid >> 6;
    const int quad = lane >> 4, m16 = lane & 15;

    if (tid < 32) f1s[tid] = f1g[rowbase + tid];
    #pragma unroll
    for (int i = 0; i < 2; i++) {
        const int idx = (tid + 256 * i) * 4;
        *(float4v*)&f2s[idx + ((idx >> 5) << 2)] = *(const float4v*)&f2g[colbase + idx];
    }

    const u32* mrow = mask + (size_t)(rowbase + r) * (N_NODES / 32) + seg * (SEGCOLS / 32);
    u32 mcur = mrow[g];    // chunk 0 word: cols g*32..g*32+31

    float4v acc[2][2];
    #pragma unroll
    for (int mt = 0; mt < 2; mt++)
        #pragma unroll
        for (int nt = 0; nt < 2; nt++) {
            acc[mt][nt][0] = 0.f; acc[mt][nt][1] = 0.f;
            acc[mt][nt][2] = 0.f; acc[mt][nt][3] = 0.f;
        }
    float ls0 = 0.f, ls1 = 0.f, ls2 = 0.f, ls3 = 0.f;

    __syncthreads();   // f1s/f2s ready

    for (int jc = 0; jc < NCHUNK; jc++) {
        u32 mnext = 0;
        if (jc + 1 < NCHUNK) mnext = mrow[(jc + 1) * 8 + g];

        // ---- weight phase: 32 consecutive cols per thread ----
        const float f1v = f1s[r];
        const float* f2p = &f2s[jc * 288 + g * 36];
        u32 packed[16];
        #pragma unroll
        for (int i = 0; i < 8; i++) {
            const float4v fv = *(const float4v*)&f2p[i * 4];
            u32 wb[4];
            #pragma unroll
            for (int e = 0; e < 4; e++) {
                const int idx = i * 4 + e;
                const int sel = ((int)(mcur << (31 - idx))) >> 31;   // 0 or -1
                float x = f1v + fv[e];
                x = fmaxf(x, SLOPEF * x);                            // leaky_relu (log2 domain)
                const float ex = __builtin_amdgcn_exp2f(x);
                const u32 wt = __float_as_uint(ex) & ((u32)sel & 0xffff0000u); // masked + bf16-trunc
                wb[e] = wt;
                if (e == 0) ls0 += __uint_as_float(wt);
                else if (e == 1) ls1 += __uint_as_float(wt);
                else if (e == 2) ls2 += __uint_as_float(wt);
                else ls3 += __uint_as_float(wt);
            }
            packed[i * 2]     = __builtin_amdgcn_perm(wb[1], wb[0], 0x07060302);
            packed[i * 2 + 1] = __builtin_amdgcn_perm(wb[3], wb[2], 0x07060302);
        }
        {
            int* pdst = (int*)&Pt[r * 264 + g * 32];
            #pragma unroll
            for (int q = 0; q < 4; q++) {
                int4v st;
                st[0] = (int)packed[q * 4 + 0]; st[1] = (int)packed[q * 4 + 1];
                st[2] = (int)packed[q * 4 + 2]; st[3] = (int)packed[q * 4 + 3];
                *(int4v*)&pdst[q * 4] = st;
            }
        }
        mcur = mnext;
        lds_barrier();

        // ---- MFMA phase: acc += P[32 x 256] @ Wh[256 x 128] (this wave's 32 feature cols) ----
        {
            const u16* b0p = WhT + (size_t)(w * 32 + m16) * N_NODES + colbase + jc * 256 + quad * 8;
            const u16* b1p = b0p + 16 * N_NODES;
            const short* a0p = &Pt[m16 * 264 + quad * 8];
            const short* a1p = a0p + 16 * 264;
            #pragma unroll
            for (int ks = 0; ks < 8; ks++) {
                const int ko = ks * 32;
                const short8v af0 = *(const short8v*)(a0p + ko);
                const short8v af1 = *(const short8v*)(a1p + ko);
                const short8v bv0 = *(const short8v*)(b0p + ko);
                const short8v bv1 = *(const short8v*)(b1p + ko);
                acc[0][0] = __builtin_amdgcn_mfma_f32_16x16x32_bf16(af0, bv0, acc[0][0], 0, 0, 0);
                acc[0][1] = __builtin_amdgcn_mfma_f32_16x16x32_bf16(af0, bv1, acc[0][1], 0, 0, 0);
                acc[1][0] = __builtin_amdgcn_mfma_f32_16x16x32_bf16(af1, bv0, acc[1][0], 0, 0, 0);
                acc[1][1] = __builtin_amdgcn_mfma_f32_16x16x32_bf16(af1, bv1, acc[1][1], 0, 0, 0);
            }
        }
        lds_barrier();
    }

    // per-row partial denominator
    rs[r][g] = (ls0 + ls1) + (ls2 + ls3);
    __syncthreads();
    if (tid < 32) {
        float s = 0.f;
        #pragma unroll
        for (int j = 0; j < 8; j++) s += rs[tid][j];
        ssum[tid] = s;
        denw[(size_t)(rowbase + tid) * NSEG + seg] = s;
    }
    __syncthreads();

    // epilogue: write partial numerator. C/D layout col=lane&15, row=quad*4+reg
    #pragma unroll
    for (int mt = 0; mt < 2; mt++) {
        #pragma unroll
        for (int nt = 0; nt < 2; nt++) {
            const int cl = w * 32 + nt * 16 + m16;
            #pragma unroll
            for (int reg = 0; reg < 4; reg++) {
                const int rl = mt * 16 + quad * 4 + reg;
                numw[((size_t)(rowbase + rl) * NSEG + seg) * D_OUT + cl] = acc[mt][nt][reg];
            }
        }
    }
}

// ---------------- Kernel 3: reduce partials, divide, write output ----------------
__global__ __launch_bounds__(256) void k3_reduce(
        const float* __restrict__ numw, const float* __restrict__ denw,
        float* __restrict__ out)
{
    const int tid = threadIdx.x;
    const int row = blockIdx.x * 2 + (tid >> 7);
    const int c   = tid & 127;
    float s = 0.f, d = 0.f;
    #pragma unroll
    for (int sg = 0; sg < NSEG; sg++) {
        s += numw[((size_t)row * NSEG + sg) * D_OUT + c];
        d += denw[(size_t)row * NSEG + sg];
    }
    out[(size_t)row * D_OUT + c] = s / d;
}

extern "C" void kernel_launch(void* const* d_in, const int* in_sizes, int n_in,
                              void* d_out, int out_size, void* d_ws, size_t ws_size,
                              hipStream_t stream) {
    const float* h   = (const float*)d_in[0];
    const int*   adj = (const int*)d_in[1];
    const float* W   = (const float*)d_in[2];
    const float* a   = (const float*)d_in[3];

    char* ws = (char*)d_ws;
    unsigned long long* mask64 = (unsigned long long*)ws;      // 8 MB
    u16*   WhT = (u16*)(ws + (size_t)8 * 1024 * 1024);         // 2 MB
    float* f1  = (float*)(ws + (size_t)10 * 1024 * 1024);      // 32 KB
    float* f2  = f1 + N_NODES;                                 // 32 KB
    float* numw = (float*)(ws + (size_t)12 * 1024 * 1024);     // 16 MB
    float* denw = (float*)(ws + (size_t)28 * 1024 * 1024);     // 128 KB

    kb_pack<<<4096, 256, 0, stream>>>(adj, mask64);
    k1_proj<<<N_NODES / 16, 256, 0, stream>>>(h, W, a, WhT, f1, f2);
    k2_attn<<<(N_NODES / 32) * NSEG, 256, 0, stream>>>((const u32*)mask64, WhT, f1, f2, numw, denw);
    k3_reduce<<<N_NODES / 2, 256, 0, stream>>>(numw, denw, (float*)d_out);
}